// Round 12
// baseline (8553.558 us; speedup 1.0000x reference)
//
#include <hip/hip_runtime.h>

// LSTM T=16384, B=32, H=96. 32 blocks x 384 thr (R8 structure, best 8196us).
// R10: heaters falsified the DVFS theory - removed. Model across R6/R8/R9:
// step = F(~500, barrier+LDS+loop) + latency-bound compute. This round trims
// both: fused transpose-reduce (lane s ends with gate-s sum: 6 cndmask+3 dpp
// vs 8 dpp+8 add+3 cndmask), rolling LDS pointers, exp2-folded activations
// (v_exp_f32 is base-2: __builtin_amdgcn_exp2f; constants pre-folded w/log2e).
// Thread (j=tid>>2, s=tid&3): all 4 gates of cell j over k-slice [24s,24s+24)
// halves via v_dot2_f32_f16 (48 weight VGPRs); lane s applies gate-s
// activation; quad bcast f,g,o; redundant c/h per quad. One barrier/step.
// h history f16 in rolling 512-step LDS buffer; fc bulk-flush every 512.

constexpr int HH   = 96;
constexpr int BB   = 32;
constexpr int TT   = 16384;
constexpr int TH   = 384;   // 6 waves
constexpr int NS   = 512;   // h history window
constexpr int ROWP = 104;   // halves per hist row: 208 B, 16B-aligned
constexpr int CH   = 2048;  // x chunk in LDS

typedef _Float16 f16x2 __attribute__((ext_vector_type(2)));

__device__ __forceinline__ float dot2_f16(f16x2 a, f16x2 b, float c) {
    float d;
    int ai = __builtin_bit_cast(int, a);
    int bi = __builtin_bit_cast(int, b);
    asm("v_dot2_f32_f16 %0, %1, %2, %3" : "=v"(d) : "v"(ai), "v"(bi), "v"(c));
    return d;
}

template <int CTRL>
__device__ __forceinline__ float dpp_add(float a, float b) {
    // a + (b cross-laned by CTRL)
    int r = __builtin_amdgcn_mov_dpp(__builtin_bit_cast(int, b), CTRL, 0xF, 0xF, true);
    return a + __builtin_bit_cast(float, r);
}
template <int CTRL>
__device__ __forceinline__ float dpp_bcast(float v) {
    int r = __builtin_amdgcn_mov_dpp(__builtin_bit_cast(int, v), CTRL, 0xF, 0xF, true);
    return __builtin_bit_cast(float, r);
}
constexpr int DPP_XOR1 = 0xB1;  // quad_perm [1,0,3,2]
constexpr int DPP_XOR2 = 0x4E;  // quad_perm [2,3,0,1]
constexpr int DPP_B1   = 0x55;
constexpr int DPP_B2   = 0xAA;
constexpr int DPP_B3   = 0xFF;

#define LOG2E 1.44269504f

__device__ __forceinline__ float tanh_f(float v) {
    // 2/(1+2^(-2*log2e*v)) - 1
    return fmaf(2.0f,
                __builtin_amdgcn_rcpf(1.0f + __builtin_amdgcn_exp2f(v * (-2.0f * LOG2E))),
                -1.0f);
}

__attribute__((amdgpu_flat_work_group_size(TH, TH), amdgpu_waves_per_eu(1, 2)))
__global__ void lstm_kernel(const float* __restrict__ x,
                            const float* __restrict__ w_ih,
                            const float* __restrict__ w_hh,
                            const float* __restrict__ b_ih,
                            const float* __restrict__ b_hh,
                            const float* __restrict__ fc_w,
                            const float* __restrict__ fc_b,
                            float* __restrict__ out) {
    __shared__ __align__(16) _Float16 hist[NS * ROWP];  // ~106 KB rolling h
    __shared__ float xs[CH];                            // 8 KB x chunk
    __shared__ float fcw_s[HH];

    const int tid = threadIdx.x;
    const int b   = blockIdx.x;
    const int j   = tid >> 2;    // cell 0..95
    const int s   = tid & 3;     // k-slice [24s,24s+24) halves; also "my gate"

    f16x2 W[4][12];
#pragma unroll
    for (int g = 0; g < 4; ++g) {
        const float* wr = w_hh + (g * HH + j) * HH + 24 * s;
#pragma unroll
        for (int m = 0; m < 12; ++m)
            W[g][m] = f16x2{(_Float16)wr[2 * m], (_Float16)wr[2 * m + 1]};
    }
#pragma unroll
    for (int g = 0; g < 4; ++g)
#pragma unroll
        for (int m = 0; m < 12; ++m) asm volatile("" : "+v"(W[g][m]));

    const float wih_s  = w_ih[s * HH + j];
    const float bias_s = b_ih[s * HH + j] + b_hh[s * HH + j];
    // sigmoid(v)=rcp(1+exp2(-log2e*v)); tanh(v)=2*rcp(1+exp2(-2log2e*v))-1
    const float e_k   = (s == 2) ? (-2.0f * LOG2E) : (-LOG2E);
    const float a_mul = (s == 2) ? 2.0f : 1.0f;
    const float a_add = (s == 2) ? -1.0f : 0.0f;

    const float fcb = fc_b[0];
    float c = 0.0f;

    for (int i = tid; i < HH; i += TH) {
        fcw_s[i] = fc_w[i];
        hist[(NS - 1) * ROWP + i] = (_Float16)0.0f;
    }

    auto flush = [&](int t0) {
        for (int i = tid; i < NS; i += TH) {
            const uint2* hr = (const uint2*)(hist + i * ROWP);
            float a = 0.0f;
#pragma unroll
            for (int m = 0; m < 24; ++m) {
                uint2 u = hr[m];
                f16x2 p0 = __builtin_bit_cast(f16x2, u.x);
                f16x2 p1 = __builtin_bit_cast(f16x2, u.y);
                a = fmaf((float)p0.x, fcw_s[4 * m + 0], a);
                a = fmaf((float)p0.y, fcw_s[4 * m + 1], a);
                a = fmaf((float)p1.x, fcw_s[4 * m + 2], a);
                a = fmaf((float)p1.y, fcw_s[4 * m + 3], a);
            }
            out[(t0 + i) * BB + b] = a + fcb + xs[(t0 + i) & (CH - 1)];
        }
    };

    // Rolling LDS pointers.
    const _Float16* rd_p = hist + (NS - 1) * ROWP + 24 * s;   // h(t-1) slice
    _Float16*       wr_p = hist + j;                          // h(t) cell slot
    const float*    xv_p = xs;

    for (int t = 0; t < TT; ++t) {
        if (t > 0 && (t & (NS - 1)) == 0) {
            flush(t - NS);
            __syncthreads();
        }
        if ((t & (CH - 1)) == 0) {
            for (int i = tid; i < CH; i += TH) xs[i] = x[(t + i) * BB + b];
            __syncthreads();
            xv_p = xs;                        // reset rolling x pointer
        }

        // ---- h(t-1) slice: 3 x ds_read_b128 off rolling pointer ----
        const uint4* hrow = (const uint4*)rd_p;
        uint4 u0 = hrow[0], u1 = hrow[1], u2 = hrow[2];
        f16x2 h2[12] = {
            __builtin_bit_cast(f16x2, u0.x), __builtin_bit_cast(f16x2, u0.y),
            __builtin_bit_cast(f16x2, u0.z), __builtin_bit_cast(f16x2, u0.w),
            __builtin_bit_cast(f16x2, u1.x), __builtin_bit_cast(f16x2, u1.y),
            __builtin_bit_cast(f16x2, u1.z), __builtin_bit_cast(f16x2, u1.w),
            __builtin_bit_cast(f16x2, u2.x), __builtin_bit_cast(f16x2, u2.y),
            __builtin_bit_cast(f16x2, u2.z), __builtin_bit_cast(f16x2, u2.w)};
        const float xv = *xv_p;

        // ---- 4 gates x 12 dots (2 chains of 6) ----
        float acc[4];
#pragma unroll
        for (int g = 0; g < 4; ++g) {
            float e0 = 0.0f, e1 = 0.0f;
#pragma unroll
            for (int m = 0; m < 6; ++m) e0 = dot2_f16(W[g][m], h2[m], e0);
#pragma unroll
            for (int m = 6; m < 12; ++m) e1 = dot2_f16(W[g][m], h2[m], e1);
            acc[g] = e0 + e1;
        }

        // ---- fused transpose-reduce: lane s ends with full gate-s sum ----
        const bool s1 = (s & 1), s2 = (s & 2) != 0;
        float ka = s1 ? acc[1] : acc[0];
        float kb = s1 ? acc[0] : acc[1];   // partner's wanted value
        float kc = s1 ? acc[3] : acc[2];
        float kd = s1 ? acc[2] : acc[3];
        float t0v = dpp_add<DPP_XOR1>(ka, kb);   // pair-sum over xor1
        float t1v = dpp_add<DPP_XOR1>(kc, kd);
        float ke = s2 ? t1v : t0v;
        float kf = s2 ? t0v : t1v;
        float pre = dpp_add<DPP_XOR2>(ke, kf);   // lane s: full sum of gate s

        pre += fmaf(xv, wih_s, bias_s);
        const float act =
            fmaf(__builtin_amdgcn_rcpf(1.0f + __builtin_amdgcn_exp2f(pre * e_k)),
                 a_mul, a_add);

        // ---- quad bcast f,g,o; redundant c/h update; h write ----
        const float fv = dpp_bcast<DPP_B1>(act);
        const float gv = dpp_bcast<DPP_B2>(act);
        const float ov = dpp_bcast<DPP_B3>(act);
        c = fmaf(fv, c, act * gv);
        const float h = ov * tanh_f(c);
        if (s == 0) *wr_p = (_Float16)h;

        // advance rolling pointers: rd must point at row (t & (NS-1)) for the
        // next iteration (t=0 read row NS-1, next reads row 0 -> reset).
        rd_p = ((t & (NS - 1)) == NS - 1 || t == 0) ? (hist + 24 * s)
                                                    : (rd_p + ROWP);
        wr_p += ROWP;
        if ((t & (NS - 1)) == NS - 1) wr_p = hist + j;
        xv_p += 1;
        __syncthreads();
    }
    flush(TT - NS);
}

extern "C" void kernel_launch(void* const* d_in, const int* in_sizes, int n_in,
                              void* d_out, int out_size, void* d_ws, size_t ws_size,
                              hipStream_t stream) {
    const float* x    = (const float*)d_in[0];
    const float* w_ih = (const float*)d_in[1];
    const float* w_hh = (const float*)d_in[2];
    const float* b_ih = (const float*)d_in[3];
    const float* b_hh = (const float*)d_in[4];
    const float* fc_w = (const float*)d_in[5];
    const float* fc_b = (const float*)d_in[6];
    float* out = (float*)d_out;

    lstm_kernel<<<dim3(BB), dim3(TH), 0, stream>>>(x, w_ih, w_hh, b_ih, b_hh,
                                                   fc_w, fc_b, out);
}

// Round 13
// 6721.776 us; speedup vs baseline: 1.2725x; 1.2725x over previous
//
#include <hip/hip_runtime.h>

// LSTM T=16384, B=32, H=96. 32 blocks x 384 thr (R8 structure = best 8196us).
// R12 deduction: VALUBusy(5.5%x8=44% active-CU) vs known ~90 instr/thread/step
// gives step=615 REAL cyc but wall=519ns -> effective clock ~1.2GHz. Bottom-up
// model matches; the only lever left is instruction count + per-step overhead.
// This round: R8 numerics restored (absmax 0.0156), plus: slot-shifted 513-row
// h history -> inner 512-step loop has NO wrap selects/branches (flush, row
// 512->0 copy, and x refill all in the outer loop); x read amortized as one
// float4 broadcast per 4 steps (unroll 4); one 12-deep dot chain per gate
// (4 gates = 4 independent chains); exp2-folded activations.
// Thread (j=tid>>2, s=tid&3): all 4 gates of cell j over k-slice [24s,24s+24)
// halves via v_dot2_f32_f16 (48 weight VGPRs); 2-level DPP quad butterfly;
// lane s applies gate-s activation; quad bcast f,g,o; redundant c/h per quad.
// One barrier/step. fc projection bulk-flushed every 512 steps.

constexpr int HH   = 96;
constexpr int BB   = 32;
constexpr int TT   = 16384;
constexpr int TH   = 384;   // 6 waves
constexpr int NS   = 512;   // h history window
constexpr int ROWP = 104;   // halves per hist row: 208 B, 16B-aligned
// hist has NS+1 rows: row r holds h(t0+r-1); row 0 seeded from prev window.

typedef _Float16 f16x2 __attribute__((ext_vector_type(2)));

__device__ __forceinline__ float dot2_f16(f16x2 a, f16x2 b, float c) {
    float d;
    int ai = __builtin_bit_cast(int, a);
    int bi = __builtin_bit_cast(int, b);
    asm("v_dot2_f32_f16 %0, %1, %2, %3" : "=v"(d) : "v"(ai), "v"(bi), "v"(c));
    return d;
}

template <int CTRL>
__device__ __forceinline__ float dpp_add(float v) {
    int r = __builtin_amdgcn_mov_dpp(__builtin_bit_cast(int, v), CTRL, 0xF, 0xF, true);
    return v + __builtin_bit_cast(float, r);
}
template <int CTRL>
__device__ __forceinline__ float dpp_bcast(float v) {
    int r = __builtin_amdgcn_mov_dpp(__builtin_bit_cast(int, v), CTRL, 0xF, 0xF, true);
    return __builtin_bit_cast(float, r);
}
constexpr int DPP_XOR1 = 0xB1;  // quad_perm [1,0,3,2]
constexpr int DPP_XOR2 = 0x4E;  // quad_perm [2,3,0,1]
constexpr int DPP_B1   = 0x55;
constexpr int DPP_B2   = 0xAA;
constexpr int DPP_B3   = 0xFF;

#define LOG2E 1.44269504f

__device__ __forceinline__ float tanh_f(float v) {
    return fmaf(2.0f,
                __builtin_amdgcn_rcpf(1.0f + __builtin_amdgcn_exp2f(v * (-2.0f * LOG2E))),
                -1.0f);
}

__attribute__((amdgpu_flat_work_group_size(TH, TH), amdgpu_waves_per_eu(1, 2)))
__global__ void lstm_kernel(const float* __restrict__ x,
                            const float* __restrict__ w_ih,
                            const float* __restrict__ w_hh,
                            const float* __restrict__ b_ih,
                            const float* __restrict__ b_hh,
                            const float* __restrict__ fc_w,
                            const float* __restrict__ fc_b,
                            float* __restrict__ out) {
    __shared__ __align__(16) _Float16 hist[(NS + 1) * ROWP];  // ~104 KB
    __shared__ __align__(16) float xs[NS];                    // 2 KB x window
    __shared__ float fcw_s[HH];

    const int tid = threadIdx.x;
    const int b   = blockIdx.x;
    const int j   = tid >> 2;    // cell 0..95
    const int s   = tid & 3;     // k-slice [24s,24s+24) halves; also "my gate"

    f16x2 W[4][12];
#pragma unroll
    for (int g = 0; g < 4; ++g) {
        const float* wr = w_hh + (g * HH + j) * HH + 24 * s;
#pragma unroll
        for (int m = 0; m < 12; ++m)
            W[g][m] = f16x2{(_Float16)wr[2 * m], (_Float16)wr[2 * m + 1]};
    }
#pragma unroll
    for (int g = 0; g < 4; ++g)
#pragma unroll
        for (int m = 0; m < 12; ++m) asm volatile("" : "+v"(W[g][m]));

    const float wih_s  = w_ih[s * HH + j];
    const float bias_s = b_ih[s * HH + j] + b_hh[s * HH + j];
    const float e_k   = (s == 2) ? (-2.0f * LOG2E) : (-LOG2E);
    const float a_mul = (s == 2) ? 2.0f : 1.0f;
    const float a_add = (s == 2) ? -1.0f : 0.0f;

    const float fcb = fc_b[0];
    float c = 0.0f;

    for (int i = tid; i < HH; i += TH) fcw_s[i] = fc_w[i];

    // Bulk fc projection for window [t0, t0+NS): h(t0+i) is in hist row i+1.
    auto flush = [&](int t0) {
        for (int i = tid; i < NS; i += TH) {
            const uint2* hr = (const uint2*)(hist + (i + 1) * ROWP);
            float a = 0.0f;
#pragma unroll
            for (int m = 0; m < 24; ++m) {
                uint2 u = hr[m];
                f16x2 p0 = __builtin_bit_cast(f16x2, u.x);
                f16x2 p1 = __builtin_bit_cast(f16x2, u.y);
                a = fmaf((float)p0.x, fcw_s[4 * m + 0], a);
                a = fmaf((float)p0.y, fcw_s[4 * m + 1], a);
                a = fmaf((float)p1.x, fcw_s[4 * m + 2], a);
                a = fmaf((float)p1.y, fcw_s[4 * m + 3], a);
            }
            out[(t0 + i) * BB + b] = a + fcb + xs[i];
        }
    };

    const _Float16* rd_p;  // h(t-1) slice, rolls by ROWP
    _Float16*       wr_p;  // h(t) cell slot, rolls by ROWP

    auto step = [&](float xv) {
        const uint4* hrow = (const uint4*)rd_p;
        uint4 u0 = hrow[0], u1 = hrow[1], u2 = hrow[2];
        f16x2 h2[12] = {
            __builtin_bit_cast(f16x2, u0.x), __builtin_bit_cast(f16x2, u0.y),
            __builtin_bit_cast(f16x2, u0.z), __builtin_bit_cast(f16x2, u0.w),
            __builtin_bit_cast(f16x2, u1.x), __builtin_bit_cast(f16x2, u1.y),
            __builtin_bit_cast(f16x2, u1.z), __builtin_bit_cast(f16x2, u1.w),
            __builtin_bit_cast(f16x2, u2.x), __builtin_bit_cast(f16x2, u2.y),
            __builtin_bit_cast(f16x2, u2.z), __builtin_bit_cast(f16x2, u2.w)};

        float acc[4];
#pragma unroll
        for (int g = 0; g < 4; ++g) {
            float e = 0.0f;
#pragma unroll
            for (int m = 0; m < 12; ++m) e = dot2_f16(W[g][m], h2[m], e);
            acc[g] = e;
        }
#pragma unroll
        for (int g = 0; g < 4; ++g) {
            acc[g] = dpp_add<DPP_XOR1>(acc[g]);
            acc[g] = dpp_add<DPP_XOR2>(acc[g]);
        }
        float pre = acc[0];
        pre = (s == 1) ? acc[1] : pre;
        pre = (s == 2) ? acc[2] : pre;
        pre = (s == 3) ? acc[3] : pre;
        pre += fmaf(xv, wih_s, bias_s);
        const float act =
            fmaf(__builtin_amdgcn_rcpf(1.0f + __builtin_amdgcn_exp2f(pre * e_k)),
                 a_mul, a_add);
        const float fv = dpp_bcast<DPP_B1>(act);
        const float gv = dpp_bcast<DPP_B2>(act);
        const float ov = dpp_bcast<DPP_B3>(act);
        c = fmaf(fv, c, act * gv);
        const float h = ov * tanh_f(c);
        if (s == 0) *wr_p = (_Float16)h;
        rd_p += ROWP;
        wr_p += ROWP;
        __syncthreads();
    };

    for (int w = 0; w < TT / NS; ++w) {
        const int t0 = w * NS;
        if (w == 0) {
            if (tid < 48) ((uint32_t*)hist)[tid] = 0u;  // row 0 = h(-1) = 0
        } else {
            flush(t0 - NS);                              // uses old xs + rows 1..512
            if (tid < 48)                                // row 512 -> row 0
                ((uint32_t*)hist)[tid] = ((const uint32_t*)(hist + NS * ROWP))[tid];
        }
        __syncthreads();
        for (int i = tid; i < NS; i += TH) xs[i] = x[(t0 + i) * BB + b];
        __syncthreads();

        rd_p = hist + 24 * s;
        wr_p = hist + ROWP + j;
        for (int tt = 0; tt < NS; tt += 4) {
            const float4 xq = *(const float4*)(xs + tt);  // broadcast, 1 per 4 steps
            step(xq.x);
            step(xq.y);
            step(xq.z);
            step(xq.w);
        }
    }
    flush(TT - NS);   // last window (loop ended with a barrier)
}

extern "C" void kernel_launch(void* const* d_in, const int* in_sizes, int n_in,
                              void* d_out, int out_size, void* d_ws, size_t ws_size,
                              hipStream_t stream) {
    const float* x    = (const float*)d_in[0];
    const float* w_ih = (const float*)d_in[1];
    const float* w_hh = (const float*)d_in[2];
    const float* b_ih = (const float*)d_in[3];
    const float* b_hh = (const float*)d_in[4];
    const float* fc_w = (const float*)d_in[5];
    const float* fc_b = (const float*)d_in[6];
    float* out = (float*)d_out;

    lstm_kernel<<<dim3(BB), dim3(TH), 0, stream>>>(x, w_ih, w_hh, b_ih, b_hh,
                                                   fc_w, fc_b, out);
}

// Round 14
// 6284.613 us; speedup vs baseline: 1.3610x; 1.0696x over previous
//
#include <hip/hip_runtime.h>

// LSTM T=16384, B=32, H=96. 32 blocks x 384 thr. R13 = 6722us, issue-bound
// (R12->R13: -15 instr -> -22% time, VALUBusy up). This round removes the
// reduce/select fat via XOR-indexed weights: thread (j,s) keeps gate (s^d) in
// slot d, so the quad butterfly b0=acc0+X1(acc1); b1=acc2+X1(acc3);
// pre=b0+X2(b1) leaves lane s with gate-s's full sum -- 6 instr vs 19
// (8 dpp_add + 3 cndmask). Per-lane add tree identical to R13 -> bit-same
// absmax. Also: ds offset immediates in the unroll-4 body (pointers advance
// once per 4 steps). Slot-shifted 513-row h history (no wrap logic in the
// inner loop), float4 x broadcast per 4 steps, exp2-folded activations,
// v_dot2_f32_f16 dots (48 weight VGPRs), one barrier/step, bulk fc flush
// every 512 steps.

constexpr int HH   = 96;
constexpr int BB   = 32;
constexpr int TT   = 16384;
constexpr int TH   = 384;   // 6 waves
constexpr int NS   = 512;   // h history window
constexpr int ROWP = 104;   // halves per hist row: 208 B, 16B-aligned

typedef _Float16 f16x2 __attribute__((ext_vector_type(2)));

__device__ __forceinline__ float dot2_f16(f16x2 a, f16x2 b, float c) {
    float d;
    int ai = __builtin_bit_cast(int, a);
    int bi = __builtin_bit_cast(int, b);
    asm("v_dot2_f32_f16 %0, %1, %2, %3" : "=v"(d) : "v"(ai), "v"(bi), "v"(c));
    return d;
}

// a + (b cross-laned by CTRL)   [2 VALU: v_mov_dpp + v_add]
template <int CTRL>
__device__ __forceinline__ float dpp_add2(float a, float b) {
    int r = __builtin_amdgcn_mov_dpp(__builtin_bit_cast(int, b), CTRL, 0xF, 0xF, true);
    return a + __builtin_bit_cast(float, r);
}
template <int CTRL>
__device__ __forceinline__ float dpp_bcast(float v) {
    int r = __builtin_amdgcn_mov_dpp(__builtin_bit_cast(int, v), CTRL, 0xF, 0xF, true);
    return __builtin_bit_cast(float, r);
}
constexpr int DPP_XOR1 = 0xB1;  // quad_perm [1,0,3,2]
constexpr int DPP_XOR2 = 0x4E;  // quad_perm [2,3,0,1]
constexpr int DPP_B1   = 0x55;
constexpr int DPP_B2   = 0xAA;
constexpr int DPP_B3   = 0xFF;

#define LOG2E 1.44269504f

__device__ __forceinline__ float tanh_f(float v) {
    return fmaf(2.0f,
                __builtin_amdgcn_rcpf(1.0f + __builtin_amdgcn_exp2f(v * (-2.0f * LOG2E))),
                -1.0f);
}

__attribute__((amdgpu_flat_work_group_size(TH, TH), amdgpu_waves_per_eu(1, 2)))
__global__ void lstm_kernel(const float* __restrict__ x,
                            const float* __restrict__ w_ih,
                            const float* __restrict__ w_hh,
                            const float* __restrict__ b_ih,
                            const float* __restrict__ b_hh,
                            const float* __restrict__ fc_w,
                            const float* __restrict__ fc_b,
                            float* __restrict__ out) {
    __shared__ __align__(16) _Float16 hist[(NS + 1) * ROWP];  // ~104 KB
    __shared__ __align__(16) float xs[NS];                    // 2 KB x window
    __shared__ float fcw_s[HH];

    const int tid = threadIdx.x;
    const int b   = blockIdx.x;
    const int j   = tid >> 2;    // cell 0..95
    const int s   = tid & 3;     // k-slice [24s,24s+24) halves; also "my gate"

    // XOR-indexed weight layout: slot d holds gate (s^d)'s row slice.
    f16x2 W[4][12];
#pragma unroll
    for (int d = 0; d < 4; ++d) {
        const float* wr = w_hh + (((s ^ d) * HH) + j) * HH + 24 * s;
#pragma unroll
        for (int m = 0; m < 12; ++m)
            W[d][m] = f16x2{(_Float16)wr[2 * m], (_Float16)wr[2 * m + 1]};
    }
#pragma unroll
    for (int d = 0; d < 4; ++d)
#pragma unroll
        for (int m = 0; m < 12; ++m) asm volatile("" : "+v"(W[d][m]));

    const float wih_s  = w_ih[s * HH + j];
    const float bias_s = b_ih[s * HH + j] + b_hh[s * HH + j];
    const float e_k   = (s == 2) ? (-2.0f * LOG2E) : (-LOG2E);
    const float a_mul = (s == 2) ? 2.0f : 1.0f;
    const float a_add = (s == 2) ? -1.0f : 0.0f;

    const float fcb = fc_b[0];
    float c = 0.0f;

    for (int i = tid; i < HH; i += TH) fcw_s[i] = fc_w[i];

    // Bulk fc projection for window [t0, t0+NS): h(t0+i) is in hist row i+1.
    auto flush = [&](int t0) {
        for (int i = tid; i < NS; i += TH) {
            const uint2* hr = (const uint2*)(hist + (i + 1) * ROWP);
            float a = 0.0f;
#pragma unroll
            for (int m = 0; m < 24; ++m) {
                uint2 u = hr[m];
                f16x2 p0 = __builtin_bit_cast(f16x2, u.x);
                f16x2 p1 = __builtin_bit_cast(f16x2, u.y);
                a = fmaf((float)p0.x, fcw_s[4 * m + 0], a);
                a = fmaf((float)p0.y, fcw_s[4 * m + 1], a);
                a = fmaf((float)p1.x, fcw_s[4 * m + 2], a);
                a = fmaf((float)p1.y, fcw_s[4 * m + 3], a);
            }
            out[(t0 + i) * BB + b] = a + fcb + xs[i];
        }
    };

    const _Float16* rd_p;  // h(t-1) slice base; advanced 4 rows at a time
    _Float16*       wr_p;  // h(t) cell slot base

    auto step = [&](float xv, const int ofs) {   // ofs: constant element offset
        const uint4* hrow = (const uint4*)(rd_p + ofs);
        uint4 u0 = hrow[0], u1 = hrow[1], u2 = hrow[2];
        f16x2 h2[12] = {
            __builtin_bit_cast(f16x2, u0.x), __builtin_bit_cast(f16x2, u0.y),
            __builtin_bit_cast(f16x2, u0.z), __builtin_bit_cast(f16x2, u0.w),
            __builtin_bit_cast(f16x2, u1.x), __builtin_bit_cast(f16x2, u1.y),
            __builtin_bit_cast(f16x2, u1.z), __builtin_bit_cast(f16x2, u1.w),
            __builtin_bit_cast(f16x2, u2.x), __builtin_bit_cast(f16x2, u2.y),
            __builtin_bit_cast(f16x2, u2.z), __builtin_bit_cast(f16x2, u2.w)};

        float acc[4];
#pragma unroll
        for (int d = 0; d < 4; ++d) {
            float e = 0.0f;
#pragma unroll
            for (int m = 0; m < 12; ++m) e = dot2_f16(W[d][m], h2[m], e);
            acc[d] = e;
        }
        // XOR butterfly: lane s ends with gate s's full sum (same add tree
        // per lane as R13 -> bit-identical result).
        const float b0 = dpp_add2<DPP_XOR1>(acc[0], acc[1]);
        const float b1 = dpp_add2<DPP_XOR1>(acc[2], acc[3]);
        float pre      = dpp_add2<DPP_XOR2>(b0, b1);

        pre += fmaf(xv, wih_s, bias_s);
        const float act =
            fmaf(__builtin_amdgcn_rcpf(1.0f + __builtin_amdgcn_exp2f(pre * e_k)),
                 a_mul, a_add);
        const float fv = dpp_bcast<DPP_B1>(act);
        const float gv = dpp_bcast<DPP_B2>(act);
        const float ov = dpp_bcast<DPP_B3>(act);
        c = fmaf(fv, c, act * gv);
        const float h = ov * tanh_f(c);
        if (s == 0) *(wr_p + ofs) = (_Float16)h;
        __syncthreads();
    };

    for (int w = 0; w < TT / NS; ++w) {
        const int t0 = w * NS;
        if (w == 0) {
            if (tid < 48) ((uint32_t*)hist)[tid] = 0u;  // row 0 = h(-1) = 0
        } else {
            flush(t0 - NS);                              // old xs + rows 1..512
            if (tid < 48)                                // row 512 -> row 0
                ((uint32_t*)hist)[tid] = ((const uint32_t*)(hist + NS * ROWP))[tid];
        }
        __syncthreads();
        for (int i = tid; i < NS; i += TH) xs[i] = x[(t0 + i) * BB + b];
        __syncthreads();

        rd_p = hist + 24 * s;
        wr_p = hist + ROWP + j;
        for (int tt = 0; tt < NS; tt += 4) {
            const float4 xq = *(const float4*)(xs + tt);  // broadcast
            step(xq.x, 0 * ROWP);
            step(xq.y, 1 * ROWP);
            step(xq.z, 2 * ROWP);
            step(xq.w, 3 * ROWP);
            rd_p += 4 * ROWP;
            wr_p += 4 * ROWP;
        }
    }
    flush(TT - NS);   // last window (loop ended with a barrier)
}

extern "C" void kernel_launch(void* const* d_in, const int* in_sizes, int n_in,
                              void* d_out, int out_size, void* d_ws, size_t ws_size,
                              hipStream_t stream) {
    const float* x    = (const float*)d_in[0];
    const float* w_ih = (const float*)d_in[1];
    const float* w_hh = (const float*)d_in[2];
    const float* b_ih = (const float*)d_in[3];
    const float* b_hh = (const float*)d_in[4];
    const float* fc_w = (const float*)d_in[5];
    const float* fc_b = (const float*)d_in[6];
    float* out = (float*)d_out;

    lstm_kernel<<<dim3(BB), dim3(TH), 0, stream>>>(x, w_ih, w_hh, b_ih, b_hh,
                                                   fc_w, fc_b, out);
}